// Round 2
// baseline (118.579 us; speedup 1.0000x reference)
//
#include <hip/hip_runtime.h>
#include <cstdint>

typedef __bf16 v8bf __attribute__((ext_vector_type(8)));
typedef float f32x4 __attribute__((ext_vector_type(4)));

#define BN_EPS 1e-5f

__device__ __forceinline__ float b2f(uint32_t u) {        // low 16 bits = bf16
    union { uint32_t i; float f; } v; v.i = u << 16; return v.f;
}
__device__ __forceinline__ uint16_t f2b(float f) {        // RNE fp32 -> bf16
    uint32_t u = __builtin_bit_cast(uint32_t, f);
    u += 0x7fffu + ((u >> 16) & 1u);
    return (uint16_t)(u >> 16);
}

// ---------------------------------------------------------------------------
// blocks 0..511 : transpose x (N,C,H,W) fp32 -> xf[(n*P+p)][c] bf16
// blocks 512..767: wT_all[512][128] bf16 = [w_value^T ; w_off^T ; w_out^T] + BN
// ---------------------------------------------------------------------------
__global__ void prep_transpose_kernel(const float* __restrict__ x,
                                      const float* __restrict__ wv, const float* __restrict__ wo,
                                      const float* __restrict__ wout,
                                      const float* __restrict__ gamma, const float* __restrict__ beta,
                                      const float* __restrict__ mean, const float* __restrict__ var,
                                      uint16_t* __restrict__ xf, uint16_t* __restrict__ wT,
                                      float* __restrict__ bnc) {
    int bid = blockIdx.x;
    if (bid < 512) {
        __shared__ float lds[64 * 65];
        int cb = bid & 1, pb = (bid >> 1) & 63, n = bid >> 7;
        int c0 = cb * 64, p0 = pb * 64;
        int l = threadIdx.x & 63, q = threadIdx.x >> 6;
        const float* xp = x + ((size_t)(n * 128 + c0)) * 4096 + p0;
#pragma unroll
        for (int i = 0; i < 16; i++) {
            int c = i * 4 + q;
            lds[l * 65 + c] = xp[(size_t)c * 4096 + l];
        }
        __syncthreads();
#pragma unroll
        for (int i = 0; i < 16; i++) {
            int pr = i * 4 + q;
            xf[((size_t)(n * 4096 + p0 + pr)) * 128 + c0 + l] = f2b(lds[pr * 65 + l]);
        }
    } else {
        int idx = (bid - 512) * 256 + threadIdx.x;
        if (idx < 512 * 128) {
            int r = idx >> 7, ci = idx & 127;
            float v;
            if (r < 128)      v = wv[ci * 128 + r];
            else if (r < 384) v = wo[ci * 256 + (r - 128)];
            else              v = wout[ci * 128 + (r - 384)];
            wT[idx] = f2b(v);
        }
        if (idx < 128) {
            float inv = gamma[idx] * rsqrtf(var[idx] + BN_EPS);
            bnc[idx] = inv;
            bnc[128 + idx] = beta[idx] - mean[idx] * inv;
        }
    }
}

// ---------------------------------------------------------------------------
// gemm1: D[m=out-col][n=pixel] = wT_all[0:384] x xf^T, K=128 fully in LDS.
// cols 0..127 -> val (n,g,p,cg) bf16 ; cols 128..383 -> om (n,p,256) bf16
// ---------------------------------------------------------------------------
__launch_bounds__(256)
__global__ void gemm1_kernel(const uint16_t* __restrict__ xf, const uint16_t* __restrict__ wT,
                             const float* __restrict__ b_value, const float* __restrict__ b_off,
                             uint16_t* __restrict__ valb, uint16_t* __restrict__ omb) {
    __shared__ __align__(16) uint16_t ldsX[128 * 136];
    __shared__ __align__(16) uint16_t ldsW[64 * 136];
    int ct = blockIdx.x;            // 0..5  -> 64 output cols
    int pt = blockIdx.y;            // 0..127 -> 128 pixels
    int p0 = pt * 128, cbase = ct * 64;
    int tid = threadIdx.x;
    int col16 = tid & 15, rowq = tid >> 4;

    const uint4* xg = (const uint4*)xf;
    uint4* lx = (uint4*)ldsX;
#pragma unroll
    for (int i = 0; i < 8; i++) {
        int row = i * 16 + rowq;
        lx[row * 17 + col16] = xg[(size_t)(p0 + row) * 16 + col16];
    }
    const uint4* wg = (const uint4*)wT;
    uint4* lw = (uint4*)ldsW;
#pragma unroll
    for (int i = 0; i < 4; i++) {
        int row = i * 16 + rowq;
        lw[row * 17 + col16] = wg[(size_t)(cbase + row) * 16 + col16];
    }
    __syncthreads();

    int wv = tid >> 6, lane = tid & 63;
    int ln = lane & 15, quad = lane >> 4;
    int cW = cbase + wv * 16 + quad * 4;          // this lane's 4 output cols
    f32x4 binit;
    if (cW < 128) binit = f32x4{b_value[cW], b_value[cW + 1], b_value[cW + 2], b_value[cW + 3]};
    else          binit = f32x4{b_off[cW - 128], b_off[cW - 127], b_off[cW - 126], b_off[cW - 125]};
    f32x4 acc[8];
#pragma unroll
    for (int t = 0; t < 8; t++) acc[t] = binit;

#pragma unroll
    for (int kk = 0; kk < 4; kk++) {
        v8bf a = *(const v8bf*)&ldsW[(wv * 16 + ln) * 136 + kk * 32 + quad * 8];
#pragma unroll
        for (int t = 0; t < 8; t++) {
            v8bf b = *(const v8bf*)&ldsX[(t * 16 + ln) * 136 + kk * 32 + quad * 8];
            acc[t] = __builtin_amdgcn_mfma_f32_16x16x32_bf16(a, b, acc[t], 0, 0, 0);
        }
    }

    int nimg = p0 >> 12, pin0 = p0 & 4095;
    if (cW < 128) {
        int g = cW >> 4, cg = cW & 15;            // cg == quad*4
#pragma unroll
        for (int t = 0; t < 8; t++) {
            int p = pin0 + t * 16 + ln;
            uint32_t u0 = (uint32_t)f2b(acc[t][0]) | ((uint32_t)f2b(acc[t][1]) << 16);
            uint32_t u1 = (uint32_t)f2b(acc[t][2]) | ((uint32_t)f2b(acc[t][3]) << 16);
            *(uint2*)&valb[(((size_t)(nimg * 8 + g) * 4096 + p) << 4) + cg] = make_uint2(u0, u1);
        }
    } else {
        int j0 = cW - 128;
#pragma unroll
        for (int t = 0; t < 8; t++) {
            int p = pin0 + t * 16 + ln;
            uint32_t u0 = (uint32_t)f2b(acc[t][0]) | ((uint32_t)f2b(acc[t][1]) << 16);
            uint32_t u1 = (uint32_t)f2b(acc[t][2]) | ((uint32_t)f2b(acc[t][3]) << 16);
            *(uint2*)&omb[((size_t)(nimg * 4096 + p) << 8) + j0] = make_uint2(u0, u1);
        }
    }
}

// ---------------------------------------------------------------------------
// fused gather + gemm3: block = 64 pixels.
// Phase 1: gather bilinear taps -> ldsA[px][ch] bf16 (MFMA A layout)
// Phase 2: D[m=pixel][n=out-ch] = A x w_out + b_out, BN, SiLU -> out NCHW fp32
// ---------------------------------------------------------------------------
__launch_bounds__(256)
__global__ void gather_gemm3_kernel(const uint16_t* __restrict__ omb, const uint16_t* __restrict__ valb,
                                    const uint16_t* __restrict__ wT,
                                    const float* __restrict__ b_out, const float* __restrict__ bnc,
                                    float* __restrict__ out) {
    __shared__ __align__(16) uint16_t ldsA[64 * 136];
    __shared__ __align__(16) uint16_t ldsW[128 * 136];
    int pt = blockIdx.x;                 // 0..255 -> 64 pixels
    int p0 = pt * 64;
    int n = p0 >> 12, pin0 = p0 & 4095;
    int tid = threadIdx.x;

    // stage w_out^T (rows 384..511 of wT)
    {
        int col16 = tid & 15, rowq = tid >> 4;
        const uint4* wg = (const uint4*)wT;
        uint4* lw = (uint4*)ldsW;
#pragma unroll
        for (int i = 0; i < 8; i++) {
            int row = i * 16 + rowq;
            lw[row * 17 + col16] = wg[(size_t)(384 + row) * 16 + col16];
        }
    }

    // ---- gather phase: g = tid>>5 so 32 consecutive lanes share a slab ----
    int g = tid >> 5, pl = tid & 31;
    const uint4* vb = (const uint4*)(valb + ((size_t)(n * 8 + g) << 16));
#pragma unroll
    for (int pp = 0; pp < 2; pp++) {
        int prow = pp * 32 + pl;             // pixel row within block, 0..63
        int p = p0 + prow;                   // global row (n*4096 + pin)
        int pin = p & 4095;
        int py = pin >> 6, px = pin & 63;

        const uint16_t* op = omb + ((size_t)p << 8) + g * 32;
        uint4 q0 = *(const uint4*)(op);
        uint4 q1 = *(const uint4*)(op + 8);
        uint4 q2 = *(const uint4*)(op + 16);
        uint2 q3 = *(const uint2*)(op + 24);
        uint32_t w[14] = {q0.x, q0.y, q0.z, q0.w, q1.x, q1.y, q1.z, q1.w,
                          q2.x, q2.y, q2.z, q2.w, q3.x, q3.y};
        float o[28];
#pragma unroll
        for (int i = 0; i < 14; i++) { o[2 * i] = b2f(w[i] & 0xffff); o[2 * i + 1] = b2f(w[i] >> 16); }

        float acc[16];
#pragma unroll
        for (int i = 0; i < 16; i++) acc[i] = 0.f;

#pragma unroll
        for (int k = 0; k < 9; k++) {
            float sx = (float)(px + (k % 3) - 1) + o[2 * k];
            float sy = (float)(py + (k / 3) - 1) + o[2 * k + 1];
            float m = o[18 + k];
            float x0f = floorf(sx), y0f = floorf(sy);
            float tx = sx - x0f, ty = sy - y0f;
            int x0 = (int)x0f, y0 = (int)y0f;
#pragma unroll
            for (int dy = 0; dy < 2; dy++) {
                int iy = y0 + dy;
                if (iy < 0 || iy > 63) continue;
                float wy = dy ? ty : 1.f - ty;
#pragma unroll
                for (int dx = 0; dx < 2; dx++) {
                    int ix = x0 + dx;
                    if (ix < 0 || ix > 63) continue;
                    float wgt = m * wy * (dx ? tx : 1.f - tx);
                    const uint4* vp = vb + ((size_t)(iy * 64 + ix)) * 2;
                    uint4 v0 = vp[0], v1 = vp[1];
                    acc[0]  += wgt * b2f(v0.x & 0xffff); acc[1]  += wgt * b2f(v0.x >> 16);
                    acc[2]  += wgt * b2f(v0.y & 0xffff); acc[3]  += wgt * b2f(v0.y >> 16);
                    acc[4]  += wgt * b2f(v0.z & 0xffff); acc[5]  += wgt * b2f(v0.z >> 16);
                    acc[6]  += wgt * b2f(v0.w & 0xffff); acc[7]  += wgt * b2f(v0.w >> 16);
                    acc[8]  += wgt * b2f(v1.x & 0xffff); acc[9]  += wgt * b2f(v1.x >> 16);
                    acc[10] += wgt * b2f(v1.y & 0xffff); acc[11] += wgt * b2f(v1.y >> 16);
                    acc[12] += wgt * b2f(v1.z & 0xffff); acc[13] += wgt * b2f(v1.z >> 16);
                    acc[14] += wgt * b2f(v1.w & 0xffff); acc[15] += wgt * b2f(v1.w >> 16);
                }
            }
        }
        uint32_t u[8];
#pragma unroll
        for (int i = 0; i < 8; i++)
            u[i] = (uint32_t)f2b(acc[2 * i]) | ((uint32_t)f2b(acc[2 * i + 1]) << 16);
        uint4* outp = (uint4*)&ldsA[prow * 136 + g * 16];
        outp[0] = make_uint4(u[0], u[1], u[2], u[3]);
        outp[1] = make_uint4(u[4], u[5], u[6], u[7]);
    }
    __syncthreads();

    // ---- MFMA phase: 4 waves x (1 m-tile of 16 px x 8 n-tiles of 16 ch) ----
    int wv = tid >> 6, lane = tid & 63;
    int ln = lane & 15, quad = lane >> 4;
    f32x4 acc[8];
#pragma unroll
    for (int ni = 0; ni < 8; ni++) {
        float b = b_out[ni * 16 + ln];
        acc[ni] = f32x4{b, b, b, b};
    }
#pragma unroll
    for (int kk = 0; kk < 4; kk++) {
        v8bf a = *(const v8bf*)&ldsA[(wv * 16 + ln) * 136 + kk * 32 + quad * 8];
#pragma unroll
        for (int ni = 0; ni < 8; ni++) {
            v8bf b = *(const v8bf*)&ldsW[(ni * 16 + ln) * 136 + kk * 32 + quad * 8];
            acc[ni] = __builtin_amdgcn_mfma_f32_16x16x32_bf16(a, b, acc[ni], 0, 0, 0);
        }
    }
    int p = pin0 + wv * 16 + quad * 4;
#pragma unroll
    for (int ni = 0; ni < 8; ni++) {
        int cc = ni * 16 + ln;
        float inv = bnc[cc], add = bnc[128 + cc];
        float4 r;
        float* rp = &r.x;
#pragma unroll
        for (int q = 0; q < 4; q++) {
            float z = acc[ni][q] * inv + add;
            rp[q] = z / (1.f + __expf(-z));
        }
        *(float4*)&out[((size_t)(n * 128 + cc) << 12) + p] = r;
    }
}

// ---------------------------------------------------------------------------
extern "C" void kernel_launch(void* const* d_in, const int* in_sizes, int n_in,
                              void* d_out, int out_size, void* d_ws, size_t ws_size,
                              hipStream_t stream) {
    const float* x       = (const float*)d_in[0];
    const float* w_value = (const float*)d_in[1];
    const float* b_value = (const float*)d_in[2];
    const float* w_off   = (const float*)d_in[3];
    const float* b_off   = (const float*)d_in[4];
    const float* w_out   = (const float*)d_in[5];
    const float* b_out   = (const float*)d_in[6];
    const float* gamma   = (const float*)d_in[7];
    const float* beta    = (const float*)d_in[8];
    const float* mean    = (const float*)d_in[9];
    const float* var     = (const float*)d_in[10];
    float* out = (float*)d_out;

    char* ws = (char*)d_ws;
    uint16_t* xf   = (uint16_t*)(ws);                        // 4 MiB
    uint16_t* valb = (uint16_t*)(ws + ((size_t)8 << 20));    // 4 MiB
    uint16_t* omb  = (uint16_t*)(ws + ((size_t)12 << 20));   // 8 MiB
    uint16_t* wT   = (uint16_t*)(ws + ((size_t)20 << 20));   // 128 KiB
    float*    bnc  = (float*)(ws + ((size_t)20 << 20) + (1 << 18)); // 1 KiB

    hipLaunchKernelGGL(prep_transpose_kernel, dim3(768), dim3(256), 0, stream,
                       x, w_value, w_off, w_out, gamma, beta, mean, var, xf, wT, bnc);
    hipLaunchKernelGGL(gemm1_kernel, dim3(6, 128), dim3(256), 0, stream,
                       xf, wT, b_value, b_off, valb, omb);
    hipLaunchKernelGGL(gather_gemm3_kernel, dim3(256), dim3(256), 0, stream,
                       omb, valb, wT, b_out, bnc, out);
}

// Round 3
// 112.359 us; speedup vs baseline: 1.0554x; 1.0554x over previous
//
#include <hip/hip_runtime.h>
#include <cstdint>

typedef __bf16 v8bf __attribute__((ext_vector_type(8)));
typedef float f32x4 __attribute__((ext_vector_type(4)));

#define BN_EPS 1e-5f

__device__ __forceinline__ float b2f(uint32_t u) {        // low 16 bits = bf16
    union { uint32_t i; float f; } v; v.i = u << 16; return v.f;
}
__device__ __forceinline__ uint16_t f2b(float f) {        // RNE fp32 -> bf16
    uint32_t u = __builtin_bit_cast(uint32_t, f);
    u += 0x7fffu + ((u >> 16) & 1u);
    return (uint16_t)(u >> 16);
}

// ---------------------------------------------------------------------------
// blocks 0..511 : transpose x (N,C,H,W) fp32 -> xf[(n*P+p)][c] bf16
// blocks 512..767: wT_all[512][128] bf16 = [w_value^T ; w_off^T ; w_out^T]
// ---------------------------------------------------------------------------
__global__ void prep_transpose_kernel(const float* __restrict__ x,
                                      const float* __restrict__ wv, const float* __restrict__ wo,
                                      const float* __restrict__ wout,
                                      uint16_t* __restrict__ xf, uint16_t* __restrict__ wT) {
    int bid = blockIdx.x;
    if (bid < 512) {
        __shared__ float lds[64 * 65];
        int cb = bid & 1, pb = (bid >> 1) & 63, n = bid >> 7;
        int c0 = cb * 64, p0 = pb * 64;
        int l = threadIdx.x & 63, q = threadIdx.x >> 6;
        const float* xp = x + ((size_t)(n * 128 + c0)) * 4096 + p0;
#pragma unroll
        for (int i = 0; i < 16; i++) {
            int c = i * 4 + q;
            lds[l * 65 + c] = xp[(size_t)c * 4096 + l];
        }
        __syncthreads();
#pragma unroll
        for (int i = 0; i < 16; i++) {
            int pr = i * 4 + q;
            xf[((size_t)(n * 4096 + p0 + pr)) * 128 + c0 + l] = f2b(lds[pr * 65 + l]);
        }
    } else {
        int idx = (bid - 512) * 256 + threadIdx.x;
        if (idx < 512 * 128) {
            int r = idx >> 7, ci = idx & 127;
            float v;
            if (r < 128)      v = wv[ci * 128 + r];
            else if (r < 384) v = wo[ci * 256 + (r - 128)];
            else              v = wout[ci * 128 + (r - 384)];
            wT[idx] = f2b(v);
        }
    }
}

// ---------------------------------------------------------------------------
// gemm1: D[m=out-col][n=pixel] = wT_all[0:384] x xf^T, K=128 fully in LDS.
// cols 0..127 -> val (n,g,p,cg) bf16 ; cols 128..383 -> om (n,p,256) bf16
// ---------------------------------------------------------------------------
__launch_bounds__(256)
__global__ void gemm1_kernel(const uint16_t* __restrict__ xf, const uint16_t* __restrict__ wT,
                             const float* __restrict__ b_value, const float* __restrict__ b_off,
                             uint16_t* __restrict__ valb, uint16_t* __restrict__ omb) {
    __shared__ __align__(16) uint16_t ldsX[128 * 136];
    __shared__ __align__(16) uint16_t ldsW[64 * 136];
    int ct = blockIdx.x;            // 0..5  -> 64 output cols
    int pt = blockIdx.y;            // 0..127 -> 128 pixels
    int p0 = pt * 128, cbase = ct * 64;
    int tid = threadIdx.x;
    int col16 = tid & 15, rowq = tid >> 4;

    const uint4* xg = (const uint4*)xf;
    uint4* lx = (uint4*)ldsX;
#pragma unroll
    for (int i = 0; i < 8; i++) {
        int row = i * 16 + rowq;
        lx[row * 17 + col16] = xg[(size_t)(p0 + row) * 16 + col16];
    }
    const uint4* wg = (const uint4*)wT;
    uint4* lw = (uint4*)ldsW;
#pragma unroll
    for (int i = 0; i < 4; i++) {
        int row = i * 16 + rowq;
        lw[row * 17 + col16] = wg[(size_t)(cbase + row) * 16 + col16];
    }
    __syncthreads();

    int wv = tid >> 6, lane = tid & 63;
    int ln = lane & 15, quad = lane >> 4;
    int cW = cbase + wv * 16 + quad * 4;          // this lane's 4 output cols
    f32x4 binit;
    if (cW < 128) binit = f32x4{b_value[cW], b_value[cW + 1], b_value[cW + 2], b_value[cW + 3]};
    else          binit = f32x4{b_off[cW - 128], b_off[cW - 127], b_off[cW - 126], b_off[cW - 125]};
    f32x4 acc[8];
#pragma unroll
    for (int t = 0; t < 8; t++) acc[t] = binit;

#pragma unroll
    for (int kk = 0; kk < 4; kk++) {
        v8bf a = *(const v8bf*)&ldsW[(wv * 16 + ln) * 136 + kk * 32 + quad * 8];
#pragma unroll
        for (int t = 0; t < 8; t++) {
            v8bf b = *(const v8bf*)&ldsX[(t * 16 + ln) * 136 + kk * 32 + quad * 8];
            acc[t] = __builtin_amdgcn_mfma_f32_16x16x32_bf16(a, b, acc[t], 0, 0, 0);
        }
    }

    int nimg = p0 >> 12, pin0 = p0 & 4095;
    if (cW < 128) {
        int g = cW >> 4, cg = cW & 15;            // cg == quad*4
#pragma unroll
        for (int t = 0; t < 8; t++) {
            int p = pin0 + t * 16 + ln;
            uint32_t u0 = (uint32_t)f2b(acc[t][0]) | ((uint32_t)f2b(acc[t][1]) << 16);
            uint32_t u1 = (uint32_t)f2b(acc[t][2]) | ((uint32_t)f2b(acc[t][3]) << 16);
            *(uint2*)&valb[(((size_t)(nimg * 8 + g) * 4096 + p) << 4) + cg] = make_uint2(u0, u1);
        }
    } else {
        int j0 = cW - 128;
#pragma unroll
        for (int t = 0; t < 8; t++) {
            int p = pin0 + t * 16 + ln;
            uint32_t u0 = (uint32_t)f2b(acc[t][0]) | ((uint32_t)f2b(acc[t][1]) << 16);
            uint32_t u1 = (uint32_t)f2b(acc[t][2]) | ((uint32_t)f2b(acc[t][3]) << 16);
            *(uint2*)&omb[((size_t)(nimg * 4096 + p) << 8) + j0] = make_uint2(u0, u1);
        }
    }
}

// ---------------------------------------------------------------------------
// fused gather + gemm3, high-occupancy layout:
// block = 16 pixels; thread = (chan-half h, group g, pixel pl) -> 1 uint4/corner
// Phase 1: gather bilinear taps -> ldsA[px][ch] bf16 (MFMA A layout)
// Phase 2: D[m=pixel][n=out-ch] = A x w_out + b_out, BN, SiLU -> out NCHW fp32
// ---------------------------------------------------------------------------
__launch_bounds__(256)
__global__ void gather_gemm3_kernel(const uint16_t* __restrict__ omb, const uint16_t* __restrict__ valb,
                                    const uint16_t* __restrict__ wT,
                                    const float* __restrict__ b_out,
                                    const float* __restrict__ gamma, const float* __restrict__ beta,
                                    const float* __restrict__ mean, const float* __restrict__ var,
                                    float* __restrict__ out) {
    __shared__ __align__(16) uint16_t ldsA[16 * 136];
    __shared__ __align__(16) uint16_t ldsW[128 * 136];
    int pt = blockIdx.x;                 // 0..1023 -> 16 pixels
    int p0 = pt * 16;
    int n = p0 >> 12, pin0 = p0 & 4095;
    int tid = threadIdx.x;

    // stage w_out^T (rows 384..511 of wT)
    {
        int col16 = tid & 15, rowq = tid >> 4;
        const uint4* wg = (const uint4*)wT;
        uint4* lw = (uint4*)ldsW;
#pragma unroll
        for (int i = 0; i < 8; i++) {
            int row = i * 16 + rowq;
            lw[row * 17 + col16] = wg[(size_t)(384 + row) * 16 + col16];
        }
    }

    // ---- gather phase ----
    int pl = tid & 15, g = (tid >> 4) & 7, h = tid >> 7;   // h = channel half
    int p = p0 + pl;
    int pin = p & 4095;
    int py = pin >> 6, px = pin & 63;

    const uint16_t* op = omb + ((size_t)p << 8) + g * 32;
    uint4 q0 = *(const uint4*)(op);
    uint4 q1 = *(const uint4*)(op + 8);
    uint4 q2 = *(const uint4*)(op + 16);
    uint2 q3 = *(const uint2*)(op + 24);
    uint32_t w[14] = {q0.x, q0.y, q0.z, q0.w, q1.x, q1.y, q1.z, q1.w,
                      q2.x, q2.y, q2.z, q2.w, q3.x, q3.y};
    float o[28];
#pragma unroll
    for (int i = 0; i < 14; i++) { o[2 * i] = b2f(w[i] & 0xffff); o[2 * i + 1] = b2f(w[i] >> 16); }

    float acc[8];
#pragma unroll
    for (int i = 0; i < 8; i++) acc[i] = 0.f;

    const uint4* vb = (const uint4*)(valb + ((size_t)(n * 8 + g) << 16)) + h;
#pragma unroll
    for (int k = 0; k < 9; k++) {
        float sx = (float)(px + (k % 3) - 1) + o[2 * k];
        float sy = (float)(py + (k / 3) - 1) + o[2 * k + 1];
        float m = o[18 + k];
        float x0f = floorf(sx), y0f = floorf(sy);
        float tx = sx - x0f, ty = sy - y0f;
        int x0 = (int)x0f, y0 = (int)y0f;
        float wy[2] = {m * (1.f - ty), m * ty};
        float wx[2] = {1.f - tx, tx};
#pragma unroll
        for (int dy = 0; dy < 2; dy++) {
            int iy = y0 + dy;
            if (iy < 0 || iy > 63) continue;
#pragma unroll
            for (int dx = 0; dx < 2; dx++) {
                int ix = x0 + dx;
                if (ix < 0 || ix > 63) continue;
                float wgt = wy[dy] * wx[dx];
                uint4 v0 = vb[((size_t)(iy * 64 + ix)) * 2];
                acc[0] += wgt * b2f(v0.x & 0xffff); acc[1] += wgt * b2f(v0.x >> 16);
                acc[2] += wgt * b2f(v0.y & 0xffff); acc[3] += wgt * b2f(v0.y >> 16);
                acc[4] += wgt * b2f(v0.z & 0xffff); acc[5] += wgt * b2f(v0.z >> 16);
                acc[6] += wgt * b2f(v0.w & 0xffff); acc[7] += wgt * b2f(v0.w >> 16);
            }
        }
    }
    uint32_t u[4];
#pragma unroll
    for (int i = 0; i < 4; i++)
        u[i] = (uint32_t)f2b(acc[2 * i]) | ((uint32_t)f2b(acc[2 * i + 1]) << 16);
    *(uint4*)&ldsA[pl * 136 + g * 16 + h * 8] = make_uint4(u[0], u[1], u[2], u[3]);
    __syncthreads();

    // ---- MFMA phase: 4 waves x 2 n-tiles of 16 ch, shared 16-px m-tile ----
    int wv = tid >> 6, lane = tid & 63;
    int ln = lane & 15, quad = lane >> 4;
    f32x4 acc2[2];
#pragma unroll
    for (int t = 0; t < 2; t++) {
        float b = b_out[(wv * 2 + t) * 16 + ln];
        acc2[t] = f32x4{b, b, b, b};
    }
#pragma unroll
    for (int kk = 0; kk < 4; kk++) {
        v8bf a = *(const v8bf*)&ldsA[ln * 136 + kk * 32 + quad * 8];
#pragma unroll
        for (int t = 0; t < 2; t++) {
            v8bf b = *(const v8bf*)&ldsW[((wv * 2 + t) * 16 + ln) * 136 + kk * 32 + quad * 8];
            acc2[t] = __builtin_amdgcn_mfma_f32_16x16x32_bf16(a, b, acc2[t], 0, 0, 0);
        }
    }
    int pp = pin0 + quad * 4;
#pragma unroll
    for (int t = 0; t < 2; t++) {
        int cc = (wv * 2 + t) * 16 + ln;
        float inv = gamma[cc] * __frsqrt_rn(var[cc] + BN_EPS);
        float add = beta[cc] - mean[cc] * inv;
        float4 r;
        float* rp = &r.x;
#pragma unroll
        for (int q = 0; q < 4; q++) {
            float z = acc2[t][q] * inv + add;
            rp[q] = z / (1.f + __expf(-z));
        }
        *(float4*)&out[((size_t)(n * 128 + cc) << 12) + pp] = r;
    }
}

// ---------------------------------------------------------------------------
extern "C" void kernel_launch(void* const* d_in, const int* in_sizes, int n_in,
                              void* d_out, int out_size, void* d_ws, size_t ws_size,
                              hipStream_t stream) {
    const float* x       = (const float*)d_in[0];
    const float* w_value = (const float*)d_in[1];
    const float* b_value = (const float*)d_in[2];
    const float* w_off   = (const float*)d_in[3];
    const float* b_off   = (const float*)d_in[4];
    const float* w_out   = (const float*)d_in[5];
    const float* b_out   = (const float*)d_in[6];
    const float* gamma   = (const float*)d_in[7];
    const float* beta    = (const float*)d_in[8];
    const float* mean    = (const float*)d_in[9];
    const float* var     = (const float*)d_in[10];
    float* out = (float*)d_out;

    char* ws = (char*)d_ws;
    uint16_t* xf   = (uint16_t*)(ws);                        // 4 MiB
    uint16_t* valb = (uint16_t*)(ws + ((size_t)8 << 20));    // 4 MiB
    uint16_t* omb  = (uint16_t*)(ws + ((size_t)12 << 20));   // 8 MiB
    uint16_t* wT   = (uint16_t*)(ws + ((size_t)20 << 20));   // 128 KiB

    hipLaunchKernelGGL(prep_transpose_kernel, dim3(768), dim3(256), 0, stream,
                       x, w_value, w_off, w_out, xf, wT);
    hipLaunchKernelGGL(gemm1_kernel, dim3(6, 128), dim3(256), 0, stream,
                       xf, wT, b_value, b_off, valb, omb);
    hipLaunchKernelGGL(gather_gemm3_kernel, dim3(1024), dim3(256), 0, stream,
                       omb, valb, wT, b_out, gamma, beta, mean, var, out);
}

// Round 4
// 111.946 us; speedup vs baseline: 1.0592x; 1.0037x over previous
//
#include <hip/hip_runtime.h>
#include <cstdint>

typedef __bf16 v8bf __attribute__((ext_vector_type(8)));
typedef float f32x4 __attribute__((ext_vector_type(4)));

#define BN_EPS 1e-5f

__device__ __forceinline__ float b2f(uint32_t u) {        // low 16 bits = bf16
    union { uint32_t i; float f; } v; v.i = u << 16; return v.f;
}
__device__ __forceinline__ uint16_t f2b(float f) {        // RNE fp32 -> bf16
    uint32_t u = __builtin_bit_cast(uint32_t, f);
    u += 0x7fffu + ((u >> 16) & 1u);
    return (uint16_t)(u >> 16);
}

// ---------------------------------------------------------------------------
// prep: wT_all[512][128] bf16 = [w_value^T ; w_off^T ; w_out^T]
// ---------------------------------------------------------------------------
__global__ void prep_kernel(const float* __restrict__ wv, const float* __restrict__ wo,
                            const float* __restrict__ wout, uint16_t* __restrict__ wT) {
    int idx = blockIdx.x * 256 + threadIdx.x;     // 256 blocks -> 65536 = 512*128
    int r = idx >> 7, ci = idx & 127;
    float v;
    if (r < 128)      v = wv[ci * 128 + r];
    else if (r < 384) v = wo[ci * 256 + (r - 128)];
    else              v = wout[ci * 128 + (r - 384)];
    wT[idx] = f2b(v);
}

// ---------------------------------------------------------------------------
// gemm1 (transpose fused): block = 32 pixels (half an H-row).
// Stage x fp32 NCHW -> ldsX[px][c] bf16 directly (coalesced global reads),
// then loop 6 chunks of 64 output cols from wT; K=128 in one shot.
// cols 0..127 -> val (n,g,p,cg) bf16 ; cols 128..383 -> om (n,p,256) bf16
// ---------------------------------------------------------------------------
__launch_bounds__(256)
__global__ void gemm1_kernel(const float* __restrict__ x, const uint16_t* __restrict__ wT,
                             const float* __restrict__ b_value, const float* __restrict__ b_off,
                             uint16_t* __restrict__ valb, uint16_t* __restrict__ omb) {
    __shared__ __align__(16) uint16_t ldsX[32 * 136];
    __shared__ __align__(16) uint16_t ldsW[64 * 136];
    int pt = blockIdx.x;                  // 0..511
    int p0 = pt * 32;
    int n = p0 >> 12, pin0 = p0 & 4095;
    int py = pin0 >> 6, px0 = pin0 & 63;
    int tid = threadIdx.x;

    // ---- stage X: 32 px x 128 ch, read x coalesced over px ----
    {
        int l = tid & 31, q = tid >> 5;   // q in 0..7
        const float* xp = x + ((size_t)(n * 128)) * 4096 + py * 64 + px0;
#pragma unroll
        for (int i = 0; i < 16; i++) {
            int c = i * 8 + q;
            ldsX[l * 136 + c] = f2b(xp[(size_t)c * 4096 + l]);
        }
    }
    __syncthreads();

    int wv = tid >> 6, lane = tid & 63;
    int ln = lane & 15, quad = lane >> 4;
    int col16 = tid & 15, rowq = tid >> 4;
    const uint4* wg = (const uint4*)wT;
    uint4* lw = (uint4*)ldsW;

    for (int ct = 0; ct < 6; ct++) {
        int cbase = ct * 64;
        if (ct > 0) __syncthreads();      // previous chunk's MFMA reads done
#pragma unroll
        for (int i = 0; i < 4; i++) {
            int row = i * 16 + rowq;
            lw[row * 17 + col16] = wg[(size_t)(cbase + row) * 16 + col16];
        }
        __syncthreads();

        int cW = cbase + wv * 16 + quad * 4;      // this lane's 4 output cols
        f32x4 binit;
        if (cW < 128) binit = f32x4{b_value[cW], b_value[cW + 1], b_value[cW + 2], b_value[cW + 3]};
        else          binit = f32x4{b_off[cW - 128], b_off[cW - 127], b_off[cW - 126], b_off[cW - 125]};
        f32x4 acc[2] = {binit, binit};

#pragma unroll
        for (int kk = 0; kk < 4; kk++) {
            v8bf a = *(const v8bf*)&ldsW[(wv * 16 + ln) * 136 + kk * 32 + quad * 8];
#pragma unroll
            for (int t = 0; t < 2; t++) {
                v8bf b = *(const v8bf*)&ldsX[(t * 16 + ln) * 136 + kk * 32 + quad * 8];
                acc[t] = __builtin_amdgcn_mfma_f32_16x16x32_bf16(a, b, acc[t], 0, 0, 0);
            }
        }

        if (cW < 128) {
            int g = cW >> 4, cg = cW & 15;        // cg == quad*4
#pragma unroll
            for (int t = 0; t < 2; t++) {
                int p = pin0 + t * 16 + ln;
                uint32_t u0 = (uint32_t)f2b(acc[t][0]) | ((uint32_t)f2b(acc[t][1]) << 16);
                uint32_t u1 = (uint32_t)f2b(acc[t][2]) | ((uint32_t)f2b(acc[t][3]) << 16);
                *(uint2*)&valb[(((size_t)(n * 8 + g) * 4096 + p) << 4) + cg] = make_uint2(u0, u1);
            }
        } else {
            int j0 = cW - 128;
#pragma unroll
            for (int t = 0; t < 2; t++) {
                int p = pin0 + t * 16 + ln;
                uint32_t u0 = (uint32_t)f2b(acc[t][0]) | ((uint32_t)f2b(acc[t][1]) << 16);
                uint32_t u1 = (uint32_t)f2b(acc[t][2]) | ((uint32_t)f2b(acc[t][3]) << 16);
                *(uint2*)&omb[((size_t)(n * 4096 + p) << 8) + j0] = make_uint2(u0, u1);
            }
        }
    }
}

// ---------------------------------------------------------------------------
// fused gather + gemm3, high-occupancy layout:
// block = 16 pixels; thread = (chan-half h, group g, pixel pl) -> 1 uint4/corner
// Phase 1: gather bilinear taps -> ldsA[px][ch] bf16 (MFMA A layout)
// Phase 2: D[m=pixel][n=out-ch] = A x w_out + b_out, BN, SiLU -> out NCHW fp32
// ---------------------------------------------------------------------------
__launch_bounds__(256)
__global__ void gather_gemm3_kernel(const uint16_t* __restrict__ omb, const uint16_t* __restrict__ valb,
                                    const uint16_t* __restrict__ wT,
                                    const float* __restrict__ b_out,
                                    const float* __restrict__ gamma, const float* __restrict__ beta,
                                    const float* __restrict__ mean, const float* __restrict__ var,
                                    float* __restrict__ out) {
    __shared__ __align__(16) uint16_t ldsA[16 * 136];
    __shared__ __align__(16) uint16_t ldsW[128 * 136];
    int pt = blockIdx.x;                 // 0..1023 -> 16 pixels
    int p0 = pt * 16;
    int n = p0 >> 12, pin0 = p0 & 4095;
    int tid = threadIdx.x;

    // stage w_out^T (rows 384..511 of wT)
    {
        int col16 = tid & 15, rowq = tid >> 4;
        const uint4* wg = (const uint4*)wT;
        uint4* lw = (uint4*)ldsW;
#pragma unroll
        for (int i = 0; i < 8; i++) {
            int row = i * 16 + rowq;
            lw[row * 17 + col16] = wg[(size_t)(384 + row) * 16 + col16];
        }
    }

    // ---- gather phase ----
    int pl = tid & 15, g = (tid >> 4) & 7, h = tid >> 7;   // h = channel half
    int p = p0 + pl;
    int pin = p & 4095;
    int py = pin >> 6, px = pin & 63;

    const uint16_t* op = omb + ((size_t)p << 8) + g * 32;
    uint4 q0 = *(const uint4*)(op);
    uint4 q1 = *(const uint4*)(op + 8);
    uint4 q2 = *(const uint4*)(op + 16);
    uint2 q3 = *(const uint2*)(op + 24);
    uint32_t w[14] = {q0.x, q0.y, q0.z, q0.w, q1.x, q1.y, q1.z, q1.w,
                      q2.x, q2.y, q2.z, q2.w, q3.x, q3.y};
    float o[28];
#pragma unroll
    for (int i = 0; i < 14; i++) { o[2 * i] = b2f(w[i] & 0xffff); o[2 * i + 1] = b2f(w[i] >> 16); }

    float acc[8];
#pragma unroll
    for (int i = 0; i < 8; i++) acc[i] = 0.f;

    const uint4* vb = (const uint4*)(valb + ((size_t)(n * 8 + g) << 16)) + h;
#pragma unroll
    for (int k = 0; k < 9; k++) {
        float sx = (float)(px + (k % 3) - 1) + o[2 * k];
        float sy = (float)(py + (k / 3) - 1) + o[2 * k + 1];
        float m = o[18 + k];
        float x0f = floorf(sx), y0f = floorf(sy);
        float tx = sx - x0f, ty = sy - y0f;
        int x0 = (int)x0f, y0 = (int)y0f;
        float wy[2] = {m * (1.f - ty), m * ty};
        float wx[2] = {1.f - tx, tx};
#pragma unroll
        for (int dy = 0; dy < 2; dy++) {
            int iy = y0 + dy;
            if (iy < 0 || iy > 63) continue;
#pragma unroll
            for (int dx = 0; dx < 2; dx++) {
                int ix = x0 + dx;
                if (ix < 0 || ix > 63) continue;
                float wgt = wy[dy] * wx[dx];
                uint4 v0 = vb[((size_t)(iy * 64 + ix)) * 2];
                acc[0] += wgt * b2f(v0.x & 0xffff); acc[1] += wgt * b2f(v0.x >> 16);
                acc[2] += wgt * b2f(v0.y & 0xffff); acc[3] += wgt * b2f(v0.y >> 16);
                acc[4] += wgt * b2f(v0.z & 0xffff); acc[5] += wgt * b2f(v0.z >> 16);
                acc[6] += wgt * b2f(v0.w & 0xffff); acc[7] += wgt * b2f(v0.w >> 16);
            }
        }
    }
    uint32_t u[4];
#pragma unroll
    for (int i = 0; i < 4; i++)
        u[i] = (uint32_t)f2b(acc[2 * i]) | ((uint32_t)f2b(acc[2 * i + 1]) << 16);
    *(uint4*)&ldsA[pl * 136 + g * 16 + h * 8] = make_uint4(u[0], u[1], u[2], u[3]);
    __syncthreads();

    // ---- MFMA phase: 4 waves x 2 n-tiles of 16 ch, shared 16-px m-tile ----
    int wv = tid >> 6, lane = tid & 63;
    int ln = lane & 15, quad = lane >> 4;
    f32x4 acc2[2];
#pragma unroll
    for (int t = 0; t < 2; t++) {
        float b = b_out[(wv * 2 + t) * 16 + ln];
        acc2[t] = f32x4{b, b, b, b};
    }
#pragma unroll
    for (int kk = 0; kk < 4; kk++) {
        v8bf a = *(const v8bf*)&ldsA[ln * 136 + kk * 32 + quad * 8];
#pragma unroll
        for (int t = 0; t < 2; t++) {
            v8bf b = *(const v8bf*)&ldsW[((wv * 2 + t) * 16 + ln) * 136 + kk * 32 + quad * 8];
            acc2[t] = __builtin_amdgcn_mfma_f32_16x16x32_bf16(a, b, acc2[t], 0, 0, 0);
        }
    }
    int pp = pin0 + quad * 4;
#pragma unroll
    for (int t = 0; t < 2; t++) {
        int cc = (wv * 2 + t) * 16 + ln;
        float inv = gamma[cc] * __frsqrt_rn(var[cc] + BN_EPS);
        float add = beta[cc] - mean[cc] * inv;
        float4 r;
        float* rp = &r.x;
#pragma unroll
        for (int q = 0; q < 4; q++) {
            float z = acc2[t][q] * inv + add;
            rp[q] = z / (1.f + __expf(-z));
        }
        *(float4*)&out[((size_t)(n * 128 + cc) << 12) + pp] = r;
    }
}

// ---------------------------------------------------------------------------
extern "C" void kernel_launch(void* const* d_in, const int* in_sizes, int n_in,
                              void* d_out, int out_size, void* d_ws, size_t ws_size,
                              hipStream_t stream) {
    const float* x       = (const float*)d_in[0];
    const float* w_value = (const float*)d_in[1];
    const float* b_value = (const float*)d_in[2];
    const float* w_off   = (const float*)d_in[3];
    const float* b_off   = (const float*)d_in[4];
    const float* w_out   = (const float*)d_in[5];
    const float* b_out   = (const float*)d_in[6];
    const float* gamma   = (const float*)d_in[7];
    const float* beta    = (const float*)d_in[8];
    const float* mean    = (const float*)d_in[9];
    const float* var     = (const float*)d_in[10];
    float* out = (float*)d_out;

    char* ws = (char*)d_ws;
    uint16_t* valb = (uint16_t*)(ws + ((size_t)8 << 20));    // 4 MiB
    uint16_t* omb  = (uint16_t*)(ws + ((size_t)12 << 20));   // 8 MiB
    uint16_t* wT   = (uint16_t*)(ws + ((size_t)20 << 20));   // 128 KiB

    hipLaunchKernelGGL(prep_kernel, dim3(256), dim3(256), 0, stream,
                       w_value, w_off, w_out, wT);
    hipLaunchKernelGGL(gemm1_kernel, dim3(512), dim3(256), 0, stream,
                       x, wT, b_value, b_off, valb, omb);
    hipLaunchKernelGGL(gather_gemm3_kernel, dim3(1024), dim3(256), 0, stream,
                       omb, valb, wT, b_out, gamma, beta, mean, var, out);
}

// Round 5
// 111.385 us; speedup vs baseline: 1.0646x; 1.0050x over previous
//
#include <hip/hip_runtime.h>
#include <cstdint>

typedef __bf16 v8bf __attribute__((ext_vector_type(8)));
typedef float f32x4 __attribute__((ext_vector_type(4)));

#define BN_EPS 1e-5f

__device__ __forceinline__ float b2f(uint32_t u) {        // low 16 bits = bf16
    union { uint32_t i; float f; } v; v.i = u << 16; return v.f;
}
__device__ __forceinline__ uint16_t f2b(float f) {        // RNE fp32 -> bf16
    uint32_t u = __builtin_bit_cast(uint32_t, f);
    u += 0x7fffu + ((u >> 16) & 1u);
    return (uint16_t)(u >> 16);
}

// ---------------------------------------------------------------------------
// prep: wT_all[512][128] bf16 = [w_value^T ; w_off^T ; w_out^T]
// ---------------------------------------------------------------------------
__global__ void prep_kernel(const float* __restrict__ wv, const float* __restrict__ wo,
                            const float* __restrict__ wout, uint16_t* __restrict__ wT) {
    int idx = blockIdx.x * 256 + threadIdx.x;     // 256 blocks -> 65536 = 512*128
    int r = idx >> 7, ci = idx & 127;
    float v;
    if (r < 128)      v = wv[ci * 128 + r];
    else if (r < 384) v = wo[ci * 256 + (r - 128)];
    else              v = wout[ci * 128 + (r - 384)];
    wT[idx] = f2b(v);
}

// ---------------------------------------------------------------------------
// gemm1 (transpose fused): block = 32 pixels (half an H-row).
// Stage x fp32 NCHW -> ldsX[px][c] bf16 directly (coalesced global reads,
// 2-channel-packed ds_write_b32), then loop 6 chunks of 64 output cols.
// cols 0..127 -> val (n,g,p,cg) bf16 ; cols 128..383 -> om (n,p,256) bf16
// ---------------------------------------------------------------------------
__launch_bounds__(256, 2)
__global__ void gemm1_kernel(const float* __restrict__ x, const uint16_t* __restrict__ wT,
                             const float* __restrict__ b_value, const float* __restrict__ b_off,
                             uint16_t* __restrict__ valb, uint16_t* __restrict__ omb) {
    __shared__ __align__(16) uint16_t ldsX[32 * 136];
    __shared__ __align__(16) uint16_t ldsW[64 * 136];
    int pt = blockIdx.x;                  // 0..511
    int p0 = pt * 32;
    int n = p0 >> 12, pin0 = p0 & 4095;
    int py = pin0 >> 6, px0 = pin0 & 63;
    int tid = threadIdx.x;

    // ---- stage X: 32 px x 128 ch, read x coalesced over px, pack 2 ch ----
    {
        int l = tid & 31, q = tid >> 5;   // q in 0..7
        const float* xp = x + ((size_t)(n * 128)) * 4096 + py * 64 + px0;
#pragma unroll
        for (int i = 0; i < 8; i++) {
            int c = i * 16 + q * 2;
            float a0 = xp[(size_t)c * 4096 + l];
            float a1 = xp[(size_t)(c + 1) * 4096 + l];
            uint32_t pk = (uint32_t)f2b(a0) | ((uint32_t)f2b(a1) << 16);
            *(uint32_t*)&ldsX[l * 136 + c] = pk;
        }
    }
    __syncthreads();

    int wv = tid >> 6, lane = tid & 63;
    int ln = lane & 15, quad = lane >> 4;
    int col16 = tid & 15, rowq = tid >> 4;
    const uint4* wg = (const uint4*)wT;
    uint4* lw = (uint4*)ldsW;

    for (int ct = 0; ct < 6; ct++) {
        int cbase = ct * 64;
        if (ct > 0) __syncthreads();      // previous chunk's MFMA reads done
#pragma unroll
        for (int i = 0; i < 4; i++) {
            int row = i * 16 + rowq;
            lw[row * 17 + col16] = wg[(size_t)(cbase + row) * 16 + col16];
        }
        __syncthreads();

        int cW = cbase + wv * 16 + quad * 4;      // this lane's 4 output cols
        f32x4 binit;
        if (cW < 128) binit = f32x4{b_value[cW], b_value[cW + 1], b_value[cW + 2], b_value[cW + 3]};
        else          binit = f32x4{b_off[cW - 128], b_off[cW - 127], b_off[cW - 126], b_off[cW - 125]};
        f32x4 acc[2] = {binit, binit};

#pragma unroll
        for (int kk = 0; kk < 4; kk++) {
            v8bf a = *(const v8bf*)&ldsW[(wv * 16 + ln) * 136 + kk * 32 + quad * 8];
#pragma unroll
            for (int t = 0; t < 2; t++) {
                v8bf b = *(const v8bf*)&ldsX[(t * 16 + ln) * 136 + kk * 32 + quad * 8];
                acc[t] = __builtin_amdgcn_mfma_f32_16x16x32_bf16(a, b, acc[t], 0, 0, 0);
            }
        }

        if (cW < 128) {
            int g = cW >> 4, cg = cW & 15;        // cg == quad*4
#pragma unroll
            for (int t = 0; t < 2; t++) {
                int p = pin0 + t * 16 + ln;
                uint32_t u0 = (uint32_t)f2b(acc[t][0]) | ((uint32_t)f2b(acc[t][1]) << 16);
                uint32_t u1 = (uint32_t)f2b(acc[t][2]) | ((uint32_t)f2b(acc[t][3]) << 16);
                *(uint2*)&valb[(((size_t)(n * 8 + g) * 4096 + p) << 4) + cg] = make_uint2(u0, u1);
            }
        } else {
            int j0 = cW - 128;
#pragma unroll
            for (int t = 0; t < 2; t++) {
                int p = pin0 + t * 16 + ln;
                uint32_t u0 = (uint32_t)f2b(acc[t][0]) | ((uint32_t)f2b(acc[t][1]) << 16);
                uint32_t u1 = (uint32_t)f2b(acc[t][2]) | ((uint32_t)f2b(acc[t][3]) << 16);
                *(uint2*)&omb[((size_t)(n * 4096 + p) << 8) + j0] = make_uint2(u0, u1);
            }
        }
    }
}

// ---------------------------------------------------------------------------
// fused gather + gemm3, high-occupancy layout + XCD-aware swizzle:
// block = 16 pixels; thread = (chan-half h, group g, pixel pl) -> 1 uint4/corner
// blockIdx swizzled so each XCD-pair owns one image n (L2-resident valb).
// ---------------------------------------------------------------------------
__launch_bounds__(256, 4)
__global__ void gather_gemm3_kernel(const uint16_t* __restrict__ omb, const uint16_t* __restrict__ valb,
                                    const uint16_t* __restrict__ wT,
                                    const float* __restrict__ b_out,
                                    const float* __restrict__ gamma, const float* __restrict__ beta,
                                    const float* __restrict__ mean, const float* __restrict__ var,
                                    float* __restrict__ out) {
    __shared__ __align__(16) uint16_t ldsA[16 * 136];
    __shared__ __align__(16) uint16_t ldsW[128 * 136];
    // swizzle: consecutive dispatch ids round-robin XCDs; give XCD-pair j>>1 image n
    int bid = blockIdx.x;                // 0..1023
    int j = bid & 7, s = bid >> 3;       // s in 0..127
    int n = j >> 1;                      // image
    int sub = (j & 1) * 128 + s;         // 0..255 tile within image
    int pin0 = sub * 16;
    int p0 = n * 4096 + pin0;
    int tid = threadIdx.x;

    // stage w_out^T (rows 384..511 of wT)
    {
        int col16 = tid & 15, rowq = tid >> 4;
        const uint4* wg = (const uint4*)wT;
        uint4* lw = (uint4*)ldsW;
#pragma unroll
        for (int i = 0; i < 8; i++) {
            int row = i * 16 + rowq;
            lw[row * 17 + col16] = wg[(size_t)(384 + row) * 16 + col16];
        }
    }

    // ---- gather phase ----
    int pl = tid & 15, g = (tid >> 4) & 7, h = tid >> 7;   // h = channel half
    int p = p0 + pl;
    int pin = pin0 + pl;
    int py = pin >> 6, px = pin & 63;

    const uint16_t* op = omb + ((size_t)p << 8) + g * 32;
    uint4 q0 = *(const uint4*)(op);
    uint4 q1 = *(const uint4*)(op + 8);
    uint4 q2 = *(const uint4*)(op + 16);
    uint2 q3 = *(const uint2*)(op + 24);
    uint32_t w[14] = {q0.x, q0.y, q0.z, q0.w, q1.x, q1.y, q1.z, q1.w,
                      q2.x, q2.y, q2.z, q2.w, q3.x, q3.y};
    float o[28];
#pragma unroll
    for (int i = 0; i < 14; i++) { o[2 * i] = b2f(w[i] & 0xffff); o[2 * i + 1] = b2f(w[i] >> 16); }

    float acc[8];
#pragma unroll
    for (int i = 0; i < 8; i++) acc[i] = 0.f;

    const uint4* vb = (const uint4*)(valb + ((size_t)(n * 8 + g) << 16)) + h;
#pragma unroll
    for (int k = 0; k < 9; k++) {
        float sx = (float)(px + (k % 3) - 1) + o[2 * k];
        float sy = (float)(py + (k / 3) - 1) + o[2 * k + 1];
        float m = o[18 + k];
        float x0f = floorf(sx), y0f = floorf(sy);
        float tx = sx - x0f, ty = sy - y0f;
        int x0 = (int)x0f, y0 = (int)y0f;
        float wy[2] = {m * (1.f - ty), m * ty};
        float wx[2] = {1.f - tx, tx};
#pragma unroll
        for (int dy = 0; dy < 2; dy++) {
            int iy = y0 + dy;
            if (iy < 0 || iy > 63) continue;
#pragma unroll
            for (int dx = 0; dx < 2; dx++) {
                int ix = x0 + dx;
                if (ix < 0 || ix > 63) continue;
                float wgt = wy[dy] * wx[dx];
                uint4 v0 = vb[((size_t)(iy * 64 + ix)) * 2];
                acc[0] += wgt * b2f(v0.x & 0xffff); acc[1] += wgt * b2f(v0.x >> 16);
                acc[2] += wgt * b2f(v0.y & 0xffff); acc[3] += wgt * b2f(v0.y >> 16);
                acc[4] += wgt * b2f(v0.z & 0xffff); acc[5] += wgt * b2f(v0.z >> 16);
                acc[6] += wgt * b2f(v0.w & 0xffff); acc[7] += wgt * b2f(v0.w >> 16);
            }
        }
    }
    uint32_t u[4];
#pragma unroll
    for (int i = 0; i < 4; i++)
        u[i] = (uint32_t)f2b(acc[2 * i]) | ((uint32_t)f2b(acc[2 * i + 1]) << 16);
    *(uint4*)&ldsA[pl * 136 + g * 16 + h * 8] = make_uint4(u[0], u[1], u[2], u[3]);
    __syncthreads();

    // ---- MFMA phase: 4 waves x 2 n-tiles of 16 ch, shared 16-px m-tile ----
    int wv = tid >> 6, lane = tid & 63;
    int ln = lane & 15, quad = lane >> 4;
    f32x4 acc2[2];
#pragma unroll
    for (int t = 0; t < 2; t++) {
        float b = b_out[(wv * 2 + t) * 16 + ln];
        acc2[t] = f32x4{b, b, b, b};
    }
#pragma unroll
    for (int kk = 0; kk < 4; kk++) {
        v8bf a = *(const v8bf*)&ldsA[ln * 136 + kk * 32 + quad * 8];
#pragma unroll
        for (int t = 0; t < 2; t++) {
            v8bf b = *(const v8bf*)&ldsW[((wv * 2 + t) * 16 + ln) * 136 + kk * 32 + quad * 8];
            acc2[t] = __builtin_amdgcn_mfma_f32_16x16x32_bf16(a, b, acc2[t], 0, 0, 0);
        }
    }
    int pp = pin0 + quad * 4;
#pragma unroll
    for (int t = 0; t < 2; t++) {
        int cc = (wv * 2 + t) * 16 + ln;
        float inv = gamma[cc] * __frsqrt_rn(var[cc] + BN_EPS);
        float add = beta[cc] - mean[cc] * inv;
        float4 r;
        float* rp = &r.x;
#pragma unroll
        for (int q = 0; q < 4; q++) {
            float z = acc2[t][q] * inv + add;
            rp[q] = z / (1.f + __expf(-z));
        }
        *(float4*)&out[((size_t)(n * 128 + cc) << 12) + pp] = r;
    }
}

// ---------------------------------------------------------------------------
extern "C" void kernel_launch(void* const* d_in, const int* in_sizes, int n_in,
                              void* d_out, int out_size, void* d_ws, size_t ws_size,
                              hipStream_t stream) {
    const float* x       = (const float*)d_in[0];
    const float* w_value = (const float*)d_in[1];
    const float* b_value = (const float*)d_in[2];
    const float* w_off   = (const float*)d_in[3];
    const float* b_off   = (const float*)d_in[4];
    const float* w_out   = (const float*)d_in[5];
    const float* b_out   = (const float*)d_in[6];
    const float* gamma   = (const float*)d_in[7];
    const float* beta    = (const float*)d_in[8];
    const float* mean    = (const float*)d_in[9];
    const float* var     = (const float*)d_in[10];
    float* out = (float*)d_out;

    char* ws = (char*)d_ws;
    uint16_t* valb = (uint16_t*)(ws + ((size_t)8 << 20));    // 4 MiB
    uint16_t* omb  = (uint16_t*)(ws + ((size_t)12 << 20));   // 8 MiB
    uint16_t* wT   = (uint16_t*)(ws + ((size_t)20 << 20));   // 128 KiB

    hipLaunchKernelGGL(prep_kernel, dim3(256), dim3(256), 0, stream,
                       w_value, w_off, w_out, wT);
    hipLaunchKernelGGL(gemm1_kernel, dim3(512), dim3(256), 0, stream,
                       x, wT, b_value, b_off, valb, omb);
    hipLaunchKernelGGL(gather_gemm3_kernel, dim3(1024), dim3(256), 0, stream,
                       omb, valb, wT, b_out, gamma, beta, mean, var, out);
}